// Round 1
// baseline (1061.047 us; speedup 1.0000x reference)
//
#include <hip/hip_runtime.h>
#include <hip/hip_bf16.h>

constexpr int D = 128;

// ---------------------------------------------------------------------------
// Fused GEMM: h0 = relu(x @ W0^T + b0), h1 = relu(x @ W1^T + b1)
// Block: 256 threads. t>>7 selects W0/W1, t&127 selects output feature.
// W row kept in 32 float4 VGPRs; x rows staged in LDS, broadcast-read.
// ---------------------------------------------------------------------------
__global__ __launch_bounds__(256) void k_gemm(
    const float* __restrict__ x,
    const float* __restrict__ W0, const float* __restrict__ b0,
    const float* __restrict__ W1, const float* __restrict__ b1,
    float* __restrict__ h0, float* __restrict__ h1, int N)
{
  constexpr int GB = 32;                 // nodes per block
  __shared__ float4 xs[GB * 32];         // 16 KB
  const int t = threadIdx.x;
  const int which = t >> 7;
  const int f = t & 127;
  const int n0 = blockIdx.x * GB;

  const float* __restrict__ W = which ? W1 : W0;
  const float bias = which ? b1[f] : b0[f];
  float4 w[32];
  const float4* Wr = reinterpret_cast<const float4*>(W + (size_t)f * D);
#pragma unroll
  for (int i = 0; i < 32; ++i) w[i] = Wr[i];

  const float4* xg = reinterpret_cast<const float4*>(x + (size_t)n0 * D);
  for (int i = t; i < GB * 32; i += 256) {
    int node = i >> 5;
    if (n0 + node < N) xs[i] = xg[i];
  }
  __syncthreads();

  float* __restrict__ H = which ? h1 : h0;
  const int nmax = min(GB, N - n0);
  for (int n = 0; n < nmax; ++n) {
    const float4* xr = &xs[n * 32];
    float acc = bias;
#pragma unroll
    for (int i = 0; i < 32; ++i) {
      float4 xv = xr[i];
      acc = fmaf(xv.x, w[i].x, acc);
      acc = fmaf(xv.y, w[i].y, acc);
      acc = fmaf(xv.z, w[i].z, acc);
      acc = fmaf(xv.w, w[i].w, acc);
    }
    acc = fmaxf(acc, 0.0f);
    H[(size_t)(n0 + n) * D + f] = acc;
  }
}

// ---------------------------------------------------------------------------
// Attention scalars: a_self = lrelu(h0 . att[:128]), a_neigh = lrelu(h1 . att[128:])
// One wave per node.
// ---------------------------------------------------------------------------
__global__ __launch_bounds__(256) void k_att(
    const float* __restrict__ h0, const float* __restrict__ h1,
    const float* __restrict__ att,
    float* __restrict__ a_self, float* __restrict__ a_neigh, int N)
{
  const int wid = blockIdx.x * 4 + (threadIdx.x >> 6);
  const int lane = threadIdx.x & 63;
  if (wid >= N) return;
  const float* r0 = h0 + (size_t)wid * D;
  const float* r1 = h1 + (size_t)wid * D;
  float s0 = fmaf(r0[lane], att[lane], r0[lane + 64] * att[lane + 64]);
  float s1 = fmaf(r1[lane], att[128 + lane], r1[lane + 64] * att[192 + lane]);
#pragma unroll
  for (int o = 32; o; o >>= 1) {
    s0 += __shfl_down(s0, o, 64);
    s1 += __shfl_down(s1, o, 64);
  }
  if (lane == 0) {
    a_self[wid]  = s0 > 0.0f ? s0 : 0.2f * s0;
    a_neigh[wid] = s1 > 0.0f ? s1 : 0.2f * s1;
  }
}

// ---------------------------------------------------------------------------
// CSR build: histogram -> exclusive scan (3 kernels) -> scatter
// ---------------------------------------------------------------------------
__global__ void k_hist(const int* __restrict__ row, int* __restrict__ cnt, int E)
{
  int e = blockIdx.x * 256 + threadIdx.x;
  if (e < E) atomicAdd(&cnt[row[e]], 1);
}

__global__ __launch_bounds__(256) void k_scan1(
    const int* __restrict__ cnt, int* __restrict__ offs, int* __restrict__ bsum, int N)
{
  __shared__ int sd[256];
  const int b = blockIdx.x, t = threadIdx.x;
  const int base = b * 1024 + t * 4;
  int v[4];
#pragma unroll
  for (int i = 0; i < 4; ++i) v[i] = (base + i < N) ? cnt[base + i] : 0;
  const int s = v[0] + v[1] + v[2] + v[3];
  sd[t] = s;
  __syncthreads();
  for (int d = 1; d < 256; d <<= 1) {
    int other = (t >= d) ? sd[t - d] : 0;
    __syncthreads();
    sd[t] += other;
    __syncthreads();
  }
  const int incl = sd[t];
  int o = incl - s;   // exclusive
#pragma unroll
  for (int i = 0; i < 4; ++i) {
    if (base + i < N) offs[base + i] = o;
    o += v[i];
  }
  if (t == 255) bsum[b] = incl;
}

__global__ __launch_bounds__(256) void k_scan2(int* __restrict__ bsum, int NB)
{
  __shared__ int sd[256];
  const int t = threadIdx.x;
  const int s = (t < NB) ? bsum[t] : 0;
  sd[t] = s;
  __syncthreads();
  for (int d = 1; d < 256; d <<= 1) {
    int other = (t >= d) ? sd[t - d] : 0;
    __syncthreads();
    sd[t] += other;
    __syncthreads();
  }
  if (t < NB) bsum[t] = sd[t] - s;   // exclusive block offsets
}

__global__ void k_scan3(int* __restrict__ offs, const int* __restrict__ bsum, int N)
{
  int i = blockIdx.x * 256 + threadIdx.x;
  if (i < N) offs[i] += bsum[i >> 10];
}

__global__ void k_scatter(
    const int* __restrict__ row, const int* __restrict__ col,
    const int* __restrict__ offs, int* __restrict__ cursor,
    int* __restrict__ colS, int E)
{
  int e = blockIdx.x * 256 + threadIdx.x;
  if (e < E) {
    int r = row[e];
    int p = offs[r] + atomicAdd(&cursor[r], 1);
    colS[p] = col[e];
  }
}

// ---------------------------------------------------------------------------
// Aggregate + both norms + final add. One 128-thread block per node.
// agg[i] = sum_j (a_self[i]+a_neigh[j]) * h1[j]; out = norm(h0)+norm(agg)
// NOTE: h0 aliases d_out; block i reads only row i, then overwrites row i.
// ---------------------------------------------------------------------------
__global__ __launch_bounds__(128) void k_agg(
    const float* __restrict__ h0, const float* __restrict__ h1,
    const float* __restrict__ a_self, const float* __restrict__ a_neigh,
    const int* __restrict__ offs, const int* __restrict__ cnt,
    const int* __restrict__ colS,
    const float* __restrict__ scale0, const float* __restrict__ offset0,
    const float* __restrict__ scale1, const float* __restrict__ offset1,
    float* __restrict__ out, int N)
{
  constexpr int CHUNK = 128;
  __shared__ int   js[CHUNK];
  __shared__ float ews[CHUNK];
  __shared__ float red[4];
  const int i = blockIdx.x;
  const int d = threadIdx.x;

  const float h0v = h0[(size_t)i * D + d];

  // stats of h0 row
  float a = h0v, b = h0v * h0v;
#pragma unroll
  for (int o = 32; o; o >>= 1) { a += __shfl_down(a, o, 64); b += __shfl_down(b, o, 64); }
  if ((d & 63) == 0) { red[d >> 6] = a; red[2 + (d >> 6)] = b; }
  __syncthreads();
  const float sum0 = red[0] + red[1], sq0 = red[2] + red[3];

  // edge aggregation
  float agg = 0.0f;
  const int start = offs[i];
  const int deg = cnt[i];
  const float as = a_self[i];
  for (int c0 = 0; c0 < deg; c0 += CHUNK) {
    const int m = min(CHUNK, deg - c0);
    __syncthreads();
    if (d < m) {
      int j = colS[start + c0 + d];
      js[d] = j;
      ews[d] = as + a_neigh[j];
    }
    __syncthreads();
#pragma unroll 4
    for (int k = 0; k < m; ++k) {
      agg = fmaf(ews[k], h1[(size_t)js[k] * D + d], agg);
    }
  }

  // stats of agg row
  float a1 = agg, b1 = agg * agg;
#pragma unroll
  for (int o = 32; o; o >>= 1) { a1 += __shfl_down(a1, o, 64); b1 += __shfl_down(b1, o, 64); }
  __syncthreads();
  if ((d & 63) == 0) { red[d >> 6] = a1; red[2 + (d >> 6)] = b1; }
  __syncthreads();
  const float sum1 = red[0] + red[1], sq1 = red[2] + red[3];

  const float inv = 1.0f / 128.0f;
  const float m0 = sum0 * inv;
  const float v0 = sq0 * inv - m0 * m0 + 1e-9f;
  const float m1 = sum1 * inv;
  const float v1 = sq1 * inv - m1 * m1 + 1e-9f;
  const float n0v = (h0v - m0) * scale0[d] * rsqrtf(v0) + offset0[d];
  const float n1v = (agg - m1) * scale1[d] * rsqrtf(v1) + offset1[d];
  out[(size_t)i * D + d] = n0v + n1v;
}

// ---------------------------------------------------------------------------
extern "C" void kernel_launch(void* const* d_in, const int* in_sizes, int n_in,
                              void* d_out, int out_size, void* d_ws, size_t ws_size,
                              hipStream_t stream)
{
  const float* x       = (const float*)d_in[0];
  const int*   row     = (const int*)d_in[1];
  const int*   col     = (const int*)d_in[2];
  const float* W0      = (const float*)d_in[3];
  const float* b0      = (const float*)d_in[4];
  const float* W1      = (const float*)d_in[5];
  const float* b1      = (const float*)d_in[6];
  const float* att     = (const float*)d_in[7];
  const float* scale0  = (const float*)d_in[8];
  const float* offset0 = (const float*)d_in[9];
  const float* scale1  = (const float*)d_in[10];
  const float* offset1 = (const float*)d_in[11];

  const int N = in_sizes[0] / D;
  const int E = in_sizes[1];

  char* ws = (char*)d_ws;
  size_t off = 0;
  auto alloc = [&](size_t bytes) -> void* {
    void* p = ws + off;
    off += (bytes + 511) & ~size_t(511);
    return p;
  };

  float* h0      = (float*)d_out;                    // alias into d_out
  float* h1      = (float*)alloc((size_t)N * D * sizeof(float));
  float* a_self  = (float*)alloc((size_t)N * sizeof(float));
  float* a_neigh = (float*)alloc((size_t)N * sizeof(float));
  int*   cnt     = (int*)alloc((size_t)N * sizeof(int));
  int*   offs    = (int*)alloc((size_t)N * sizeof(int));
  int*   cursor  = (int*)alloc((size_t)N * sizeof(int));
  int*   bsum    = (int*)alloc(1024 * sizeof(int));
  int*   colS    = (int*)alloc((size_t)E * sizeof(int));

  hipMemsetAsync(cnt, 0, (size_t)N * sizeof(int), stream);
  hipMemsetAsync(cursor, 0, (size_t)N * sizeof(int), stream);

  k_gemm<<<(N + 31) / 32, 256, 0, stream>>>(x, W0, b0, W1, b1, h0, h1, N);
  k_att<<<(N + 3) / 4, 256, 0, stream>>>(h0, h1, att, a_self, a_neigh, N);
  k_hist<<<(E + 255) / 256, 256, 0, stream>>>(row, cnt, E);
  const int NB1 = (N + 1023) / 1024;
  k_scan1<<<NB1, 256, 0, stream>>>(cnt, offs, bsum, N);
  k_scan2<<<1, 256, 0, stream>>>(bsum, NB1);
  k_scan3<<<(N + 255) / 256, 256, 0, stream>>>(offs, bsum, N);
  k_scatter<<<(E + 255) / 256, 256, 0, stream>>>(row, col, offs, cursor, colS, E);
  k_agg<<<N, 128, 0, stream>>>(h0, h1, a_self, a_neigh, offs, cnt, colS,
                               scale0, offset0, scale1, offset1, (float*)d_out, N);
}

// Round 2
// 652.563 us; speedup vs baseline: 1.6260x; 1.6260x over previous
//
#include <hip/hip_runtime.h>
#include <hip/hip_bf16.h>

constexpr int D = 128;

// ---------------------------------------------------------------------------
// Fused GEMM: h0 = relu(x @ W0^T + b0), h1 = relu(x @ W1^T + b1)
// Register-blocked tile: BM=128 nodes x BN=64 features, K=128 in 2 chunks of 64.
// blockIdx.y in [0,4): 0,1 -> W0/h0 cols 0/64; 2,3 -> W1/h1 cols 0/64.
// 256 threads, each owns an 8x4 microtile (nodes {tn*4+i, 64+tn*4+i}, feats tf*4+j).
// LDS transposed with padded strides (132 / 68 floats) -> compute reads are
// 2-way-or-free bank aliased; staging writes 2-way (free).
// ---------------------------------------------------------------------------
__global__ __launch_bounds__(256) void k_gemm(
    const float* __restrict__ x,
    const float* __restrict__ W0, const float* __restrict__ b0,
    const float* __restrict__ W1, const float* __restrict__ b1,
    float* __restrict__ h0, float* __restrict__ h1, int N)
{
  constexpr int XS_STRIDE = 132;   // 128 + 4, keeps 16B alignment, 4k%32 spread
  constexpr int WS_STRIDE = 68;    // 64 + 4
  __shared__ float xs_t[64 * XS_STRIDE];  // [k][node]  33792 B
  __shared__ float ws_t[64 * WS_STRIDE];  // [k][feat]  17408 B

  const int t  = threadIdx.x;
  const int nb = blockIdx.x;
  const int fb = blockIdx.y;
  const int n0 = nb * 128;

  const float* __restrict__ W    = (fb < 2) ? W0 : W1;
  const float* __restrict__ bias = (fb < 2) ? b0 : b1;
  float* __restrict__ H          = (fb < 2) ? h0 : h1;
  const int frow0 = (fb & 1) * 64;

  // compute-thread mapping: tf fast (coalesced stores), tn slow
  const int tf = t & 15;        // feature group: feats tf*4 .. tf*4+3
  const int tn = t >> 4;        // node group

  // staging mappings
  const int x_nq = t >> 1;      // 0..127
  const int x_kq = t & 1;       // 0..1   (k = x_kq*32 + i*4)
  const int w_f  = t >> 2;      // 0..63
  const int w_kq = t & 3;       // 0..3   (k = w_kq*4 + i*16)

  float acc[8][4];
#pragma unroll
  for (int i = 0; i < 8; ++i)
#pragma unroll
    for (int j = 0; j < 4; ++j) acc[i][j] = 0.0f;

  const bool x_ok = (n0 + x_nq) < N;
  const float* xrow = x + (size_t)(n0 + x_nq) * D;
  const float* wrow = W + (size_t)(frow0 + w_f) * D;

  for (int c = 0; c < 2; ++c) {
    const int k0 = c * 64;
    if (c) __syncthreads();  // don't overwrite LDS while others still compute

    // stage x chunk: 8 float4 per thread, transpose into xs_t[k][n]
#pragma unroll
    for (int i = 0; i < 8; ++i) {
      const int k = x_kq * 32 + i * 4;
      float4 v = x_ok ? *reinterpret_cast<const float4*>(xrow + k0 + k)
                      : make_float4(0.f, 0.f, 0.f, 0.f);
      xs_t[(k + 0) * XS_STRIDE + x_nq] = v.x;
      xs_t[(k + 1) * XS_STRIDE + x_nq] = v.y;
      xs_t[(k + 2) * XS_STRIDE + x_nq] = v.z;
      xs_t[(k + 3) * XS_STRIDE + x_nq] = v.w;
    }
    // stage W chunk: 4 float4 per thread
#pragma unroll
    for (int i = 0; i < 4; ++i) {
      const int k = w_kq * 4 + i * 16;
      float4 v = *reinterpret_cast<const float4*>(wrow + k0 + k);
      ws_t[(k + 0) * WS_STRIDE + w_f] = v.x;
      ws_t[(k + 1) * WS_STRIDE + w_f] = v.y;
      ws_t[(k + 2) * WS_STRIDE + w_f] = v.z;
      ws_t[(k + 3) * WS_STRIDE + w_f] = v.w;
    }
    __syncthreads();

#pragma unroll 4
    for (int k = 0; k < 64; ++k) {
      const float4 a0 = *reinterpret_cast<const float4*>(&xs_t[k * XS_STRIDE + tn * 4]);
      const float4 a1 = *reinterpret_cast<const float4*>(&xs_t[k * XS_STRIDE + 64 + tn * 4]);
      const float4 bvec = *reinterpret_cast<const float4*>(&ws_t[k * WS_STRIDE + tf * 4]);
      const float av[8] = {a0.x, a0.y, a0.z, a0.w, a1.x, a1.y, a1.z, a1.w};
      const float bv[4] = {bvec.x, bvec.y, bvec.z, bvec.w};
#pragma unroll
      for (int i = 0; i < 8; ++i)
#pragma unroll
        for (int j = 0; j < 4; ++j)
          acc[i][j] = fmaf(av[i], bv[j], acc[i][j]);
    }
  }

  const float4 b4 = *reinterpret_cast<const float4*>(&bias[frow0 + tf * 4]);
#pragma unroll
  for (int i = 0; i < 8; ++i) {
    const int nq = (i < 4) ? (tn * 4 + i) : (64 + tn * 4 + (i - 4));
    const int node = n0 + nq;
    if (node < N) {
      float4 r;
      r.x = fmaxf(acc[i][0] + b4.x, 0.0f);
      r.y = fmaxf(acc[i][1] + b4.y, 0.0f);
      r.z = fmaxf(acc[i][2] + b4.z, 0.0f);
      r.w = fmaxf(acc[i][3] + b4.w, 0.0f);
      *reinterpret_cast<float4*>(&H[(size_t)node * D + frow0 + tf * 4]) = r;
    }
  }
}

// ---------------------------------------------------------------------------
// Attention scalars: a_self = lrelu(h0 . att[:128]), a_neigh = lrelu(h1 . att[128:])
// One wave per node.
// ---------------------------------------------------------------------------
__global__ __launch_bounds__(256) void k_att(
    const float* __restrict__ h0, const float* __restrict__ h1,
    const float* __restrict__ att,
    float* __restrict__ a_self, float* __restrict__ a_neigh, int N)
{
  const int wid = blockIdx.x * 4 + (threadIdx.x >> 6);
  const int lane = threadIdx.x & 63;
  if (wid >= N) return;
  const float* r0 = h0 + (size_t)wid * D;
  const float* r1 = h1 + (size_t)wid * D;
  float s0 = fmaf(r0[lane], att[lane], r0[lane + 64] * att[lane + 64]);
  float s1 = fmaf(r1[lane], att[128 + lane], r1[lane + 64] * att[192 + lane]);
#pragma unroll
  for (int o = 32; o; o >>= 1) {
    s0 += __shfl_down(s0, o, 64);
    s1 += __shfl_down(s1, o, 64);
  }
  if (lane == 0) {
    a_self[wid]  = s0 > 0.0f ? s0 : 0.2f * s0;
    a_neigh[wid] = s1 > 0.0f ? s1 : 0.2f * s1;
  }
}

// ---------------------------------------------------------------------------
// CSR build: histogram -> exclusive scan (3 kernels) -> scatter
// ---------------------------------------------------------------------------
__global__ void k_hist(const int* __restrict__ row, int* __restrict__ cnt, int E)
{
  int e = blockIdx.x * 256 + threadIdx.x;
  if (e < E) atomicAdd(&cnt[row[e]], 1);
}

__global__ __launch_bounds__(256) void k_scan1(
    const int* __restrict__ cnt, int* __restrict__ offs, int* __restrict__ bsum, int N)
{
  __shared__ int sd[256];
  const int b = blockIdx.x, t = threadIdx.x;
  const int base = b * 1024 + t * 4;
  int v[4];
#pragma unroll
  for (int i = 0; i < 4; ++i) v[i] = (base + i < N) ? cnt[base + i] : 0;
  const int s = v[0] + v[1] + v[2] + v[3];
  sd[t] = s;
  __syncthreads();
  for (int d = 1; d < 256; d <<= 1) {
    int other = (t >= d) ? sd[t - d] : 0;
    __syncthreads();
    sd[t] += other;
    __syncthreads();
  }
  const int incl = sd[t];
  int o = incl - s;   // exclusive
#pragma unroll
  for (int i = 0; i < 4; ++i) {
    if (base + i < N) offs[base + i] = o;
    o += v[i];
  }
  if (t == 255) bsum[b] = incl;
}

__global__ __launch_bounds__(256) void k_scan2(int* __restrict__ bsum, int NB)
{
  __shared__ int sd[256];
  const int t = threadIdx.x;
  const int s = (t < NB) ? bsum[t] : 0;
  sd[t] = s;
  __syncthreads();
  for (int d = 1; d < 256; d <<= 1) {
    int other = (t >= d) ? sd[t - d] : 0;
    __syncthreads();
    sd[t] += other;
    __syncthreads();
  }
  if (t < NB) bsum[t] = sd[t] - s;   // exclusive block offsets
}

__global__ void k_scan3(int* __restrict__ offs, const int* __restrict__ bsum, int N)
{
  int i = blockIdx.x * 256 + threadIdx.x;
  if (i < N) offs[i] += bsum[i >> 10];
}

__global__ void k_scatter(
    const int* __restrict__ row, const int* __restrict__ col,
    const int* __restrict__ offs, int* __restrict__ cursor,
    int* __restrict__ colS, int E)
{
  int e = blockIdx.x * 256 + threadIdx.x;
  if (e < E) {
    int r = row[e];
    int p = offs[r] + atomicAdd(&cursor[r], 1);
    colS[p] = col[e];
  }
}

// ---------------------------------------------------------------------------
// Aggregate + both norms + final add. One 128-thread block per node.
// agg[i] = sum_j (a_self[i]+a_neigh[j]) * h1[j]; out = norm(h0)+norm(agg)
// NOTE: h0 aliases d_out; block i reads only row i, then overwrites row i.
// ---------------------------------------------------------------------------
__global__ __launch_bounds__(128) void k_agg(
    const float* __restrict__ h0, const float* __restrict__ h1,
    const float* __restrict__ a_self, const float* __restrict__ a_neigh,
    const int* __restrict__ offs, const int* __restrict__ cnt,
    const int* __restrict__ colS,
    const float* __restrict__ scale0, const float* __restrict__ offset0,
    const float* __restrict__ scale1, const float* __restrict__ offset1,
    float* __restrict__ out, int N)
{
  constexpr int CHUNK = 128;
  __shared__ int   js[CHUNK];
  __shared__ float ews[CHUNK];
  __shared__ float red[4];
  const int i = blockIdx.x;
  const int d = threadIdx.x;

  const float h0v = h0[(size_t)i * D + d];

  // stats of h0 row
  float a = h0v, b = h0v * h0v;
#pragma unroll
  for (int o = 32; o; o >>= 1) { a += __shfl_down(a, o, 64); b += __shfl_down(b, o, 64); }
  if ((d & 63) == 0) { red[d >> 6] = a; red[2 + (d >> 6)] = b; }
  __syncthreads();
  const float sum0 = red[0] + red[1], sq0 = red[2] + red[3];

  // edge aggregation
  float agg = 0.0f;
  const int start = offs[i];
  const int deg = cnt[i];
  const float as = a_self[i];
  for (int c0 = 0; c0 < deg; c0 += CHUNK) {
    const int m = min(CHUNK, deg - c0);
    __syncthreads();
    if (d < m) {
      int j = colS[start + c0 + d];
      js[d] = j;
      ews[d] = as + a_neigh[j];
    }
    __syncthreads();
#pragma unroll 4
    for (int k = 0; k < m; ++k) {
      agg = fmaf(ews[k], h1[(size_t)js[k] * D + d], agg);
    }
  }

  // stats of agg row
  float a1 = agg, b1 = agg * agg;
#pragma unroll
  for (int o = 32; o; o >>= 1) { a1 += __shfl_down(a1, o, 64); b1 += __shfl_down(b1, o, 64); }
  __syncthreads();
  if ((d & 63) == 0) { red[d >> 6] = a1; red[2 + (d >> 6)] = b1; }
  __syncthreads();
  const float sum1 = red[0] + red[1], sq1 = red[2] + red[3];

  const float inv = 1.0f / 128.0f;
  const float m0 = sum0 * inv;
  const float v0 = sq0 * inv - m0 * m0 + 1e-9f;
  const float m1 = sum1 * inv;
  const float v1 = sq1 * inv - m1 * m1 + 1e-9f;
  const float n0v = (h0v - m0) * scale0[d] * rsqrtf(v0) + offset0[d];
  const float n1v = (agg - m1) * scale1[d] * rsqrtf(v1) + offset1[d];
  out[(size_t)i * D + d] = n0v + n1v;
}

// ---------------------------------------------------------------------------
extern "C" void kernel_launch(void* const* d_in, const int* in_sizes, int n_in,
                              void* d_out, int out_size, void* d_ws, size_t ws_size,
                              hipStream_t stream)
{
  const float* x       = (const float*)d_in[0];
  const int*   row     = (const int*)d_in[1];
  const int*   col     = (const int*)d_in[2];
  const float* W0      = (const float*)d_in[3];
  const float* b0      = (const float*)d_in[4];
  const float* W1      = (const float*)d_in[5];
  const float* b1      = (const float*)d_in[6];
  const float* att     = (const float*)d_in[7];
  const float* scale0  = (const float*)d_in[8];
  const float* offset0 = (const float*)d_in[9];
  const float* scale1  = (const float*)d_in[10];
  const float* offset1 = (const float*)d_in[11];

  const int N = in_sizes[0] / D;
  const int E = in_sizes[1];

  char* ws = (char*)d_ws;
  size_t off = 0;
  auto alloc = [&](size_t bytes) -> void* {
    void* p = ws + off;
    off += (bytes + 511) & ~size_t(511);
    return p;
  };

  float* h0      = (float*)d_out;                    // alias into d_out
  float* h1      = (float*)alloc((size_t)N * D * sizeof(float));
  float* a_self  = (float*)alloc((size_t)N * sizeof(float));
  float* a_neigh = (float*)alloc((size_t)N * sizeof(float));
  int*   cnt     = (int*)alloc((size_t)N * sizeof(int));
  int*   offs    = (int*)alloc((size_t)N * sizeof(int));
  int*   cursor  = (int*)alloc((size_t)N * sizeof(int));
  int*   bsum    = (int*)alloc(1024 * sizeof(int));
  int*   colS    = (int*)alloc((size_t)E * sizeof(int));

  hipMemsetAsync(cnt, 0, (size_t)N * sizeof(int), stream);
  hipMemsetAsync(cursor, 0, (size_t)N * sizeof(int), stream);

  dim3 ggrid((N + 127) / 128, 4);
  k_gemm<<<ggrid, 256, 0, stream>>>(x, W0, b0, W1, b1, h0, h1, N);
  k_att<<<(N + 3) / 4, 256, 0, stream>>>(h0, h1, att, a_self, a_neigh, N);
  k_hist<<<(E + 255) / 256, 256, 0, stream>>>(row, cnt, E);
  const int NB1 = (N + 1023) / 1024;
  k_scan1<<<NB1, 256, 0, stream>>>(cnt, offs, bsum, N);
  k_scan2<<<1, 256, 0, stream>>>(bsum, NB1);
  k_scan3<<<(N + 255) / 256, 256, 0, stream>>>(offs, bsum, N);
  k_scatter<<<(E + 255) / 256, 256, 0, stream>>>(row, col, offs, cursor, colS, E);
  k_agg<<<N, 128, 0, stream>>>(h0, h1, a_self, a_neigh, offs, cnt, colS,
                               scale0, offset0, scale1, offset1, (float*)d_out, N);
}